// Round 3
// baseline (235.015 us; speedup 1.0000x reference)
//
#include <hip/hip_runtime.h>
#include <hip/hip_cooperative_groups.h>
#include <math.h>

namespace cg = cooperative_groups;

typedef unsigned short u16;
typedef __bf16 bf16x8 __attribute__((ext_vector_type(8)));
typedef float f32x4 __attribute__((ext_vector_type(4)));

// ---------- helpers ----------
__device__ inline u16 bf16_rn(float x) {
    unsigned u = __float_as_uint(x);
    return (u16)((u + 0x7FFFu + ((u >> 16) & 1u)) >> 16);
}
__device__ inline uint2 pack4(u16 a, u16 b, u16 c, u16 d) {
    uint2 r;
    r.x = (unsigned)a | ((unsigned)b << 16);
    r.y = (unsigned)c | ((unsigned)d << 16);
    return r;
}
__device__ inline uint2 pack4f(float a, float b, float c, float d) {
    return pack4(bf16_rn(a), bf16_rn(b), bf16_rn(c), bf16_rn(d));
}
__device__ inline f32x4 mfma16(bf16x8 a, bf16x8 b, f32x4 c) {
    return __builtin_amdgcn_mfma_f32_16x16x32_bf16(a, b, c, 0, 0, 0);
}

#define LDK 68
// LDS layout (bytes), max over phases:
//  phase1: zs2[2][64] f32                        @0     (512)
//  phase2: T[64][65] f32 @0 (16640) | red[8][64] @16640 (2048) | hs @18688 (256) | ds @18944 (256)
//  phase3/4: As[2][64*LDK] u16 @0 (17408) | Bs @17408 (17408) | sv[1024] f32 @34816 (4096) | redA[8] @38912 (32)
#define SMEM_BYTES 39040

__global__ __launch_bounds__(512) void k_fused(
    const float* __restrict__ x, const float* __restrict__ q, const float* __restrict__ p,
    const float* __restrict__ W1, const float* __restrict__ b1,
    const float* __restrict__ W2, const float* __restrict__ b2, const float* __restrict__ W3,
    float* __restrict__ out,
    float* __restrict__ H1, float* __restrict__ D1, float* __restrict__ Avec,
    float* __restrict__ Vacc, float* __restrict__ Upart,
    u16* __restrict__ Ah, u16* __restrict__ WTh, u16* __restrict__ W2h, u16* __restrict__ Sh) {
    __shared__ __align__(16) char smem[SMEM_BYTES];
    cg::grid_group grid = cg::this_grid();
    int tid = threadIdx.x, bid = blockIdx.x;

    // ================= Phase 1: W1 GEMV partials + A-block bf16 cast + zeroing =================
    if (bid < 96) {
        float* zs2 = (float*)smem;  // [2][64]
        int half = tid >> 8, t2 = tid & 255;
        int jc = bid * 2 + half;       // 0..191
        int k = (jc & 3) * 256 + t2;   // 4 k-groups
        int j0 = (jc >> 2) * 64;       // 48 j-chunks (64-aligned, never straddles x/q/p)
        if (t2 < 64) {
            int j = j0 + t2;
            zs2[half * 64 + t2] = (j < 1024) ? x[j] : (j < 2048 ? q[j - 1024] : p[j - 2048]);
        }
        __syncthreads();
        const float* zsl = zs2 + half * 64;
        float acc = 0.f;
        if (j0 < 1024) {
            // A-block rows: fuse bf16 cast with the GEMV read (W1 A-block read once)
#pragma unroll 8
            for (int j = 0; j < 64; ++j) {
                float v = W1[(j0 + j) * 1024 + k];
                Ah[(j0 + j) * 1024 + k] = bf16_rn(v);
                acc += zsl[j] * v;
            }
        } else {
#pragma unroll 8
            for (int j = 0; j < 64; ++j) acc += zsl[j] * W1[(j0 + j) * 1024 + k];
        }
        Upart[(jc >> 2) * 1024 + k] = acc;
    } else if (bid == 96) {
        for (int s = tid; s < 768; s += 512) {
            int idx = s * 4;  // 3072 floats: out[2048] + Vacc[1024]
            if (idx < 2048) *(float4*)(out + idx) = make_float4(0.f, 0.f, 0.f, 0.f);
            else *(float4*)(Vacc + idx - 2048) = make_float4(0.f, 0.f, 0.f, 0.f);
        }
    }
    grid.sync();

    // ================= Phase 2: reduce U -> h1/d1, W2 -> W2h, transpose+d1-scale -> WTh, Vacc =================
    {
        float(*T)[65] = (float(*)[65])smem;
        float* red = (float*)(smem + 16640);  // [8][64]
        float* hs = (float*)(smem + 18688);
        float* ds = (float*)(smem + 18944);
        int k0 = (bid >> 4) * 64, m0 = (bid & 15) * 64;
        {
            int g = tid >> 6, lk = tid & 63;  // 8 groups x 6 chunks
            float u = 0.f;
#pragma unroll
            for (int c = 0; c < 6; ++c) u += Upart[(g * 6 + c) * 1024 + k0 + lk];
            red[g * 64 + lk] = u;
        }
        __syncthreads();
        if (tid < 64) {
            float u = 0.f;
#pragma unroll
            for (int g = 0; g < 8; ++g) u += red[g * 64 + tid];
            float h = tanhf(u + b1[k0 + tid]);
            hs[tid] = h;
            ds[tid] = 1.f - h * h;
            if (m0 == 0) { H1[k0 + tid] = h; D1[k0 + tid] = 1.f - h * h; }
        }
        __syncthreads();
        int t = tid;
        int rr = (t & 255) >> 4, cc = (t & 15) * 4;
        if (t < 256) {
            float4 vp = make_float4(0.f, 0.f, 0.f, 0.f);
#pragma unroll
            for (int j = 0; j < 4; ++j) {
                int r = rr + j * 16;
                float4 v = *(const float4*)(W2 + (k0 + r) * 1024 + m0 + cc);
                T[r][cc + 0] = v.x; T[r][cc + 1] = v.y; T[r][cc + 2] = v.z; T[r][cc + 3] = v.w;
                *(uint2*)&W2h[(k0 + r) * 1024 + m0 + cc] = pack4f(v.x, v.y, v.z, v.w);
                float hk = hs[r];
                vp.x += hk * v.x; vp.y += hk * v.y; vp.z += hk * v.z; vp.w += hk * v.w;
            }
            vp.x += __shfl_xor(vp.x, 16); vp.y += __shfl_xor(vp.y, 16);
            vp.z += __shfl_xor(vp.z, 16); vp.w += __shfl_xor(vp.w, 16);
            vp.x += __shfl_xor(vp.x, 32); vp.y += __shfl_xor(vp.y, 32);
            vp.z += __shfl_xor(vp.z, 32); vp.w += __shfl_xor(vp.w, 32);
            if (((t & 63) >> 4) == 0) {
                atomicAdd(&Vacc[m0 + cc + 0], vp.x);
                atomicAdd(&Vacc[m0 + cc + 1], vp.y);
                atomicAdd(&Vacc[m0 + cc + 2], vp.z);
                atomicAdd(&Vacc[m0 + cc + 3], vp.w);
            }
        }
        __syncthreads();
        if (t < 256) {
#pragma unroll
            for (int j = 0; j < 4; ++j) {
                int mrow = rr + j * 16;
                float f0 = T[cc + 0][mrow] * ds[cc + 0];
                float f1 = T[cc + 1][mrow] * ds[cc + 1];
                float f2 = T[cc + 2][mrow] * ds[cc + 2];
                float f3 = T[cc + 3][mrow] * ds[cc + 3];
                *(uint2*)&WTh[(m0 + mrow) * 1024 + k0 + cc] = pack4f(f0, f1, f2, f3);
            }
        }
    }
    grid.sync();

    // ================= Phase 3: GEMM1 (Ah x WTh -> Sh) + Avec GEMV (4 rows/block) =================
    {
        u16* As = (u16*)smem;                   // [2][64*LDK]
        u16* Bs = (u16*)(smem + 17408);
        float* sv = (float*)(smem + 34816);     // [1024]
        float* redA = (float*)(smem + 38912);   // [8]
        int lane = tid & 63, wv = tid >> 6;
        int kh = wv >> 2, wy = (wv >> 1) & 1, wx = wv & 1;
        int i0 = (bid >> 4) * 64, m0 = (bid & 15) * 64;
        int srow = tid >> 3, sseg = (tid & 7) * 8;
        int ldso = srow * LDK + sseg;
        const u16* ap = Ah + (i0 + srow) * 1024 + sseg;
        const u16* bp = WTh + (m0 + srow) * 1024 + sseg;
        int tx = lane & 15, qy = lane >> 4;
        int koff = kh * 32 + qy * 8;
        int raA0 = (wy * 32 + tx) * LDK + koff, raA1 = raA0 + 16 * LDK;
        int rbB0 = (wx * 32 + tx) * LDK + koff, rbB1 = rbB0 + 16 * LDK;
        f32x4 acc[2][2];
#pragma unroll
        for (int a = 0; a < 2; ++a)
#pragma unroll
            for (int b = 0; b < 2; ++b) acc[a][b] = (f32x4){0.f, 0.f, 0.f, 0.f};

        uint4 pa1 = *(const uint4*)(ap + 64);
        uint4 pc1 = *(const uint4*)(bp + 64);
        *(uint4*)&As[ldso] = *(const uint4*)(ap);
        *(uint4*)&Bs[ldso] = *(const uint4*)(bp);

        for (int k0 = 0; k0 < 1024; k0 += 64) {
            int buf = ((k0 >> 6) & 1) * 4352;
            int kn2 = (k0 + 128) & 1023;
            uint4 pa2 = *(const uint4*)(ap + kn2);
            uint4 pc2 = *(const uint4*)(bp + kn2);
            __syncthreads();
            bf16x8 aH0 = *(const bf16x8*)&As[buf + raA0];
            bf16x8 aH1 = *(const bf16x8*)&As[buf + raA1];
            bf16x8 bH0 = *(const bf16x8*)&Bs[buf + rbB0];
            bf16x8 bH1 = *(const bf16x8*)&Bs[buf + rbB1];
            acc[0][0] = mfma16(aH0, bH0, acc[0][0]);
            acc[0][1] = mfma16(aH0, bH1, acc[0][1]);
            acc[1][0] = mfma16(aH1, bH0, acc[1][0]);
            acc[1][1] = mfma16(aH1, bH1, acc[1][1]);
            int nb = buf ^ 4352;
            *(uint4*)&As[nb + ldso] = pa1;
            *(uint4*)&Bs[nb + ldso] = pc1;
            pa1 = pa2; pc1 = pc2;
        }
        __syncthreads();
        f32x4* mrg = (f32x4*)As;
        if (kh == 1) {
#pragma unroll
            for (int si = 0; si < 2; ++si)
#pragma unroll
                for (int sj = 0; sj < 2; ++sj)
                    mrg[(((wy * 2 + wx) * 4 + si * 2 + sj) * 4 + qy) * 16 + tx] = acc[si][sj];
        }
        __syncthreads();
        if (kh == 0) {
#pragma unroll
            for (int si = 0; si < 2; ++si)
#pragma unroll
                for (int sj = 0; sj < 2; ++sj) {
                    f32x4 o = mrg[(((wy * 2 + wx) * 4 + si * 2 + sj) * 4 + qy) * 16 + tx];
                    acc[si][sj][0] += o[0]; acc[si][sj][1] += o[1];
                    acc[si][sj][2] += o[2]; acc[si][sj][3] += o[3];
                }
#pragma unroll
            for (int sj = 0; sj < 2; ++sj) {
                int m = m0 + wx * 32 + sj * 16 + tx;
                float hv = tanhf(Vacc[m] + b2[m]);
                float d2 = 1.f - hv * hv;
                float cm = -2.f * hv * d2 * W3[m];  // Cvec inline
#pragma unroll
                for (int si = 0; si < 2; ++si) {
                    int ib = i0 + wy * 32 + si * 16 + qy * 4;
#pragma unroll
                    for (int r = 0; r < 4; ++r)
                        Sh[(ib + r) * 1024 + m] = bf16_rn(acc[si][sj][r] * cm);
                }
            }
        }
        // ---- Avec tail folded in: this block computes Avec[bid*4 .. bid*4+3] ----
        __syncthreads();
#pragma unroll
        for (int j = 0; j < 2; ++j) {
            int m = tid + j * 512;
            float h = tanhf(Vacc[m] + b2[m]);
            sv[m] = (1.f - h * h) * W3[m];
        }
        __syncthreads();
        {
            int kA = bid * 4 + (wv >> 1);
            int off = (wv & 1) * 512 + lane * 8;
            const float* wr = W2 + kA * 1024 + off;
            const float* svp = sv + off;
            float a = 0.f;
#pragma unroll
            for (int j = 0; j < 8; ++j) a += wr[j] * svp[j];
#pragma unroll
            for (int o = 1; o < 64; o <<= 1) a += __shfl_xor(a, o);
            if (lane == 0) redA[wv] = a;
        }
        __syncthreads();
        if (tid < 4) {
            int kA = bid * 4 + tid;
            Avec[kA] = -2.f * H1[kA] * D1[kA] * (redA[tid * 2] + redA[tid * 2 + 1]);
        }
    }
    grid.sync();

    // ================= Phase 4: GEMM2 (Sh x W2h) + fused epilogue -> out =================
    {
        u16* As = (u16*)smem;
        u16* Bs = (u16*)(smem + 17408);
        int lane = tid & 63, wv = tid >> 6;
        int kh = wv >> 2, wy = (wv >> 1) & 1, wx = wv & 1;
        int i0 = (bid >> 4) * 64, k0g = (bid & 15) * 64;
        int srow = tid >> 3, sseg = (tid & 7) * 8;
        int ldso = srow * LDK + sseg;
        const u16* ap = Sh + (i0 + srow) * 1024 + sseg;
        const u16* bp = W2h + (k0g + srow) * 1024 + sseg;
        int tx = lane & 15, qy = lane >> 4;
        int koff = kh * 32 + qy * 8;
        int raA0 = (wy * 32 + tx) * LDK + koff, raA1 = raA0 + 16 * LDK;
        int rbB0 = (wx * 32 + tx) * LDK + koff, rbB1 = rbB0 + 16 * LDK;
        f32x4 acc[2][2];
#pragma unroll
        for (int a = 0; a < 2; ++a)
#pragma unroll
            for (int b = 0; b < 2; ++b) acc[a][b] = (f32x4){0.f, 0.f, 0.f, 0.f};

        uint4 pa1 = *(const uint4*)(ap + 64);
        uint4 pc1 = *(const uint4*)(bp + 64);
        *(uint4*)&As[ldso] = *(const uint4*)(ap);
        *(uint4*)&Bs[ldso] = *(const uint4*)(bp);

        for (int m0 = 0; m0 < 1024; m0 += 64) {
            int buf = ((m0 >> 6) & 1) * 4352;
            int mn2 = (m0 + 128) & 1023;
            uint4 pa2 = *(const uint4*)(ap + mn2);
            uint4 pc2 = *(const uint4*)(bp + mn2);
            __syncthreads();
            bf16x8 aH0 = *(const bf16x8*)&As[buf + raA0];
            bf16x8 aH1 = *(const bf16x8*)&As[buf + raA1];
            bf16x8 bH0 = *(const bf16x8*)&Bs[buf + rbB0];
            bf16x8 bH1 = *(const bf16x8*)&Bs[buf + rbB1];
            acc[0][0] = mfma16(aH0, bH0, acc[0][0]);
            acc[0][1] = mfma16(aH0, bH1, acc[0][1]);
            acc[1][0] = mfma16(aH1, bH0, acc[1][0]);
            acc[1][1] = mfma16(aH1, bH1, acc[1][1]);
            int nb = buf ^ 4352;
            *(uint4*)&As[nb + ldso] = pa1;
            *(uint4*)&Bs[nb + ldso] = pc1;
            pa1 = pa2; pc1 = pc2;
        }
        __syncthreads();
        f32x4* mrg = (f32x4*)As;
        if (kh == 1) {
#pragma unroll
            for (int si = 0; si < 2; ++si)
#pragma unroll
                for (int sj = 0; sj < 2; ++sj)
                    mrg[(((wy * 2 + wx) * 4 + si * 2 + sj) * 4 + qy) * 16 + tx] = acc[si][sj];
        }
        __syncthreads();
        if (kh == 0) {
#pragma unroll
            for (int si = 0; si < 2; ++si)
#pragma unroll
                for (int sj = 0; sj < 2; ++sj) {
                    f32x4 o = mrg[(((wy * 2 + wx) * 4 + si * 2 + sj) * 4 + qy) * 16 + tx];
                    acc[si][sj][0] += o[0]; acc[si][sj][1] += o[1];
                    acc[si][sj][2] += o[2]; acc[si][sj][3] += o[3];
                }
            // fused epilogue: DR = Avec[k]*W1[i,k] + D1[k]*Wm[i,k]; dot with q/p rows of W1
            int kk[2];
            float d1v[2], avv[2];
#pragma unroll
            for (int sj = 0; sj < 2; ++sj) {
                kk[sj] = k0g + wx * 32 + sj * 16 + tx;
                d1v[sj] = D1[kk[sj]];
                avv[sj] = Avec[kk[sj]];
            }
#pragma unroll
            for (int si = 0; si < 2; ++si) {
                int ib = i0 + wy * 32 + si * 16 + qy * 4;
#pragma unroll
                for (int r = 0; r < 4; ++r) {
                    int i = ib + r;
                    float pq = 0.f, pp = 0.f;
#pragma unroll
                    for (int sj = 0; sj < 2; ++sj) {
                        int k = kk[sj];
                        float dr = avv[sj] * W1[i * 1024 + k] + d1v[sj] * acc[si][sj][r];
                        pq += W1[(1024 + i) * 1024 + k] * dr;
                        pp += W1[(2048 + i) * 1024 + k] * dr;
                    }
                    for (int o = 1; o < 16; o <<= 1) {
                        pq += __shfl_xor(pq, o);
                        pp += __shfl_xor(pp, o);
                    }
                    if (tx == 0) {
                        atomicAdd(&out[i], pp);
                        atomicAdd(&out[1024 + i], -pq);
                    }
                }
            }
        }
    }
}

extern "C" void kernel_launch(void* const* d_in, const int* in_sizes, int n_in,
                              void* d_out, int out_size, void* d_ws, size_t ws_size,
                              hipStream_t stream) {
    const float* x = (const float*)d_in[0];
    const float* q = (const float*)d_in[1];
    const float* p = (const float*)d_in[2];
    const float* W1 = (const float*)d_in[3];
    const float* b1 = (const float*)d_in[4];
    const float* W2 = (const float*)d_in[5];
    const float* b2 = (const float*)d_in[6];
    const float* W3 = (const float*)d_in[7];
    float* out = (float*)d_out;
    float* ws = (float*)d_ws;
    float* H1 = ws, *D1 = ws + 1024, *Avec = ws + 2048, *Vacc = ws + 3072;
    float* Upart = ws + 4096;  // 48*1024 floats
    u16* u0 = (u16*)(ws + 65536);
    u16* Ah = u0;
    u16* WTh = u0 + 1048576;
    u16* W2h = u0 + 2097152;
    u16* Sh = u0 + 3145728;

    void* args[] = {&x, &q, &p, &W1, &b1, &W2, &b2, &W3, &out,
                    &H1, &D1, &Avec, &Vacc, &Upart, &Ah, &WTh, &W2h, &Sh};
    hipLaunchCooperativeKernel((const void*)k_fused, dim3(256), dim3(512), args, 0, stream);
}

// Round 4
// 164.820 us; speedup vs baseline: 1.4259x; 1.4259x over previous
//
#include <hip/hip_runtime.h>
#include <math.h>

typedef unsigned short u16;
typedef __bf16 bf16x8 __attribute__((ext_vector_type(8)));
typedef float f32x4 __attribute__((ext_vector_type(4)));

// ---------- helpers ----------
__device__ inline u16 bf16_rn(float x) {
    unsigned u = __float_as_uint(x);
    return (u16)((u + 0x7FFFu + ((u >> 16) & 1u)) >> 16);
}
__device__ inline uint2 pack4(u16 a, u16 b, u16 c, u16 d) {
    uint2 r;
    r.x = (unsigned)a | ((unsigned)b << 16);
    r.y = (unsigned)c | ((unsigned)d << 16);
    return r;
}
__device__ inline uint2 pack4f(float a, float b, float c, float d) {
    return pack4(bf16_rn(a), bf16_rn(b), bf16_rn(c), bf16_rn(d));
}
__device__ inline f32x4 mfma16(bf16x8 a, bf16x8 b, f32x4 c) {
    return __builtin_amdgcn_mfma_f32_16x16x32_bf16(a, b, c, 0, 0, 0);
}

// ---------- k_pre: u-partials + cast ALL of W1 (3072x1024) to bf16 + zero out/Vacc ----------
__global__ __launch_bounds__(256) void k_pre(const float* __restrict__ x,
                                             const float* __restrict__ q,
                                             const float* __restrict__ p,
                                             const float* __restrict__ W1,
                                             u16* __restrict__ Ah,
                                             float* __restrict__ Upart,
                                             float* __restrict__ out,
                                             float* __restrict__ Vacc) {
    int b = blockIdx.x, t = threadIdx.x;
    if (b < 192) {
        int jc = b;                    // 0..191
        int k = (jc & 3) * 256 + t;    // 4 k-groups
        int j0 = (jc >> 2) * 64;       // 48 j-chunks (64-aligned, never straddles x/q/p)
        __shared__ float zs[64];
        if (t < 64) {
            int j = j0 + t;
            zs[t] = (j < 1024) ? x[j] : (j < 2048 ? q[j - 1024] : p[j - 2048]);
        }
        __syncthreads();
        float acc = 0.f;
        // all rows: fuse bf16 cast with the GEMV read (W1 read exactly once here)
#pragma unroll 8
        for (int j = 0; j < 64; ++j) {
            float v = W1[(j0 + j) * 1024 + k];
            Ah[(j0 + j) * 1024 + k] = bf16_rn(v);
            acc += zs[j] * v;
        }
        Upart[(jc >> 2) * 1024 + k] = acc;  // plain store, no atomics
    } else {
        int idx = ((b - 192) * 256 + t) * 4;  // 3072 floats: out[2048] + Vacc[1024]
        if (idx < 2048) *(float4*)(out + idx) = make_float4(0.f, 0.f, 0.f, 0.f);
        else *(float4*)(Vacc + idx - 2048) = make_float4(0.f, 0.f, 0.f, 0.f);
    }
}

// ---------- k_w2v: reduce U -> h1/d1, transpose+d1-scale W2 -> WTh (bf16), Vacc partials ----------
__global__ __launch_bounds__(256) void k_w2v(const float* __restrict__ W2,
                                             const float* __restrict__ b1,
                                             const float* __restrict__ Upart,
                                             float* __restrict__ H1g, float* __restrict__ D1g,
                                             u16* __restrict__ WTh,
                                             float* __restrict__ Vacc) {
    __shared__ float T[64][65];
    __shared__ float hs[64], ds[64];
    __shared__ float red[4][64];
    int k0 = blockIdx.y * 64, m0 = blockIdx.x * 64;
    int t = threadIdx.x;
    {
        int lk = t & 63, g = t >> 6;  // 4 groups x 12 chunks
        float u = 0.f;
#pragma unroll
        for (int c = 0; c < 12; ++c) u += Upart[(g * 12 + c) * 1024 + k0 + lk];
        red[g][lk] = u;
    }
    __syncthreads();
    if (t < 64) {
        float u = red[0][t] + red[1][t] + red[2][t] + red[3][t];
        float h = tanhf(u + b1[k0 + t]);
        hs[t] = h;
        ds[t] = 1.f - h * h;
        if (m0 == 0) { H1g[k0 + t] = h; D1g[k0 + t] = 1.f - h * h; }
    }
    __syncthreads();
    int rr = t >> 4, cc = (t & 15) * 4;
    float4 vp = make_float4(0.f, 0.f, 0.f, 0.f);
#pragma unroll
    for (int j = 0; j < 4; ++j) {
        int r = rr + j * 16;
        float4 v = *(const float4*)(W2 + (k0 + r) * 1024 + m0 + cc);
        T[r][cc + 0] = v.x; T[r][cc + 1] = v.y; T[r][cc + 2] = v.z; T[r][cc + 3] = v.w;
        float hk = hs[r];
        vp.x += hk * v.x; vp.y += hk * v.y; vp.z += hk * v.z; vp.w += hk * v.w;
    }
    vp.x += __shfl_xor(vp.x, 16); vp.y += __shfl_xor(vp.y, 16);
    vp.z += __shfl_xor(vp.z, 16); vp.w += __shfl_xor(vp.w, 16);
    vp.x += __shfl_xor(vp.x, 32); vp.y += __shfl_xor(vp.y, 32);
    vp.z += __shfl_xor(vp.z, 32); vp.w += __shfl_xor(vp.w, 32);
    if (((t & 63) >> 4) == 0) {
        atomicAdd(&Vacc[m0 + cc + 0], vp.x);
        atomicAdd(&Vacc[m0 + cc + 1], vp.y);
        atomicAdd(&Vacc[m0 + cc + 2], vp.z);
        atomicAdd(&Vacc[m0 + cc + 3], vp.w);
    }
    __syncthreads();
#pragma unroll
    for (int j = 0; j < 4; ++j) {
        int mrow = rr + j * 16;
        float f0 = T[cc + 0][mrow] * ds[cc + 0];
        float f1 = T[cc + 1][mrow] * ds[cc + 1];
        float f2 = T[cc + 2][mrow] * ds[cc + 2];
        float f3 = T[cc + 3][mrow] * ds[cc + 3];
        *(uint2*)&WTh[(m0 + mrow) * 1024 + k0 + cc] = pack4f(f0, f1, f2, f3);
    }
}

// ---------- k_big: blocks 0..255 = triple-GEMM (Mx,Mq,Mp share B) + C*Mx*Mq epilogue;
//            blocks 256..319 = Avec + f32 avterm tail. Both only atomicAdd out -> no ordering dep. ----------
#define LDK 68
#define TILE_E (64 * LDK)          // 4352 u16 per tile
#define SMEM_BYTES 69632           // 8 tiles x 8704 B
__global__ __launch_bounds__(512) void k_big(const u16* __restrict__ Ah,
                                             const u16* __restrict__ WTh,
                                             const float* __restrict__ W1,
                                             const float* __restrict__ W2,
                                             const float* __restrict__ b2,
                                             const float* __restrict__ W3,
                                             const float* __restrict__ Vacc,
                                             const float* __restrict__ H1,
                                             const float* __restrict__ D1,
                                             float* __restrict__ out) {
    __shared__ __align__(16) char smem[SMEM_BYTES];
    int tid = threadIdx.x, bid = blockIdx.x;

    if (bid >= 256) {
        // ================= mid tail: Avec (local) + f32 avterm -> out =================
        float* sv = (float*)smem;          // [1024] d2*W3
        float* avL = (float*)(smem + 4096);  // [16]
        int kb = (bid - 256) * 16;
#pragma unroll
        for (int j = 0; j < 2; ++j) {
            int m = tid + j * 512;
            float h = tanhf(Vacc[m] + b2[m]);
            sv[m] = (1.f - h * h) * W3[m];
        }
        __syncthreads();
        {
            int row = tid >> 5, seg = tid & 31;  // 16 rows x 32 segs of 32 m
            const float* wr = W2 + (kb + row) * 1024 + seg * 32;
            const float* svp = sv + seg * 32;
            float a = 0.f;
#pragma unroll 8
            for (int j = 0; j < 32; ++j) a += wr[j] * svp[j];
            a += __shfl_xor(a, 1); a += __shfl_xor(a, 2); a += __shfl_xor(a, 4);
            a += __shfl_xor(a, 8); a += __shfl_xor(a, 16);
            if (seg == 0) avL[row] = -2.f * H1[kb + row] * D1[kb + row] * a;
        }
        __syncthreads();
        {
            int kloc = tid & 15, ig = tid >> 4;  // 16 k-lanes x 32 i-rows per iter
            float av = avL[kloc];
            int k = kb + kloc;
            for (int it = 0; it < 32; ++it) {
                int i = it * 32 + ig;
                float wx = W1[i * 1024 + k];
                float wq = W1[(1024 + i) * 1024 + k];
                float wp = W1[(2048 + i) * 1024 + k];
                float tv = av * wx;
                float pq = tv * wq, pp = tv * wp;
                pq += __shfl_xor(pq, 1); pp += __shfl_xor(pp, 1);
                pq += __shfl_xor(pq, 2); pp += __shfl_xor(pp, 2);
                pq += __shfl_xor(pq, 4); pp += __shfl_xor(pp, 4);
                pq += __shfl_xor(pq, 8); pp += __shfl_xor(pp, 8);
                if (kloc == 0) {
                    atomicAdd(&out[i], pp);
                    atomicAdd(&out[1024 + i], -pq);
                }
            }
        }
        return;
    }

    // ================= triple-GEMM =================
    u16* Axs = (u16*)smem;                       // [2][TILE_E]
    u16* Aqs = (u16*)(smem + 17408);
    u16* Aps = (u16*)(smem + 34816);
    u16* Bs  = (u16*)(smem + 52224);
    int lane = tid & 63, wv = tid >> 6;
    int kh = wv >> 2, wy = (wv >> 1) & 1, wx = wv & 1;
    int i0 = (bid >> 4) * 64, m0 = (bid & 15) * 64;
    int srow = tid >> 3, sseg = (tid & 7) * 8;
    int ldso = srow * LDK + sseg;
    const u16* apx = Ah + (i0 + srow) * 1024 + sseg;
    const u16* apq = Ah + (1024 + i0 + srow) * 1024 + sseg;
    const u16* app = Ah + (2048 + i0 + srow) * 1024 + sseg;
    const u16* bp  = WTh + (m0 + srow) * 1024 + sseg;
    int tx = lane & 15, qy = lane >> 4;
    int koff = kh * 32 + qy * 8;
    int raA0 = (wy * 32 + tx) * LDK + koff, raA1 = raA0 + 16 * LDK;
    int rbB0 = (wx * 32 + tx) * LDK + koff, rbB1 = rbB0 + 16 * LDK;
    f32x4 accX[2][2], accQ[2][2], accP[2][2];
#pragma unroll
    for (int a = 0; a < 2; ++a)
#pragma unroll
        for (int b = 0; b < 2; ++b) {
            accX[a][b] = (f32x4){0.f, 0.f, 0.f, 0.f};
            accQ[a][b] = (f32x4){0.f, 0.f, 0.f, 0.f};
            accP[a][b] = (f32x4){0.f, 0.f, 0.f, 0.f};
        }

    uint4 px1 = *(const uint4*)(apx + 64);
    uint4 pq1 = *(const uint4*)(apq + 64);
    uint4 pp1 = *(const uint4*)(app + 64);
    uint4 pb1 = *(const uint4*)(bp + 64);
    *(uint4*)&Axs[ldso] = *(const uint4*)(apx);
    *(uint4*)&Aqs[ldso] = *(const uint4*)(apq);
    *(uint4*)&Aps[ldso] = *(const uint4*)(app);
    *(uint4*)&Bs[ldso]  = *(const uint4*)(bp);

    for (int k0 = 0; k0 < 1024; k0 += 64) {
        int buf = ((k0 >> 6) & 1) * TILE_E;
        int kn2 = (k0 + 128) & 1023;  // depth-2 prefetch (wraps; staged but never read at tail)
        uint4 px2 = *(const uint4*)(apx + kn2);
        uint4 pq2 = *(const uint4*)(apq + kn2);
        uint4 pp2 = *(const uint4*)(app + kn2);
        uint4 pb2 = *(const uint4*)(bp + kn2);
        __syncthreads();
        bf16x8 bH0 = *(const bf16x8*)&Bs[buf + rbB0];
        bf16x8 bH1 = *(const bf16x8*)&Bs[buf + rbB1];
        bf16x8 aX0 = *(const bf16x8*)&Axs[buf + raA0];
        bf16x8 aX1 = *(const bf16x8*)&Axs[buf + raA1];
        bf16x8 aQ0 = *(const bf16x8*)&Aqs[buf + raA0];
        bf16x8 aQ1 = *(const bf16x8*)&Aqs[buf + raA1];
        bf16x8 aP0 = *(const bf16x8*)&Aps[buf + raA0];
        bf16x8 aP1 = *(const bf16x8*)&Aps[buf + raA1];
        accX[0][0] = mfma16(aX0, bH0, accX[0][0]);
        accX[0][1] = mfma16(aX0, bH1, accX[0][1]);
        accX[1][0] = mfma16(aX1, bH0, accX[1][0]);
        accX[1][1] = mfma16(aX1, bH1, accX[1][1]);
        accQ[0][0] = mfma16(aQ0, bH0, accQ[0][0]);
        accQ[0][1] = mfma16(aQ0, bH1, accQ[0][1]);
        accQ[1][0] = mfma16(aQ1, bH0, accQ[1][0]);
        accQ[1][1] = mfma16(aQ1, bH1, accQ[1][1]);
        accP[0][0] = mfma16(aP0, bH0, accP[0][0]);
        accP[0][1] = mfma16(aP0, bH1, accP[0][1]);
        accP[1][0] = mfma16(aP1, bH0, accP[1][0]);
        accP[1][1] = mfma16(aP1, bH1, accP[1][1]);
        int nb = buf ^ TILE_E;
        *(uint4*)&Axs[nb + ldso] = px1;
        *(uint4*)&Aqs[nb + ldso] = pq1;
        *(uint4*)&Aps[nb + ldso] = pp1;
        *(uint4*)&Bs[nb + ldso]  = pb1;
        px1 = px2; pq1 = pq2; pp1 = pp2; pb1 = pb2;
    }
    // merge K-halves through LDS (reuse Axs region as 16 KB scratch), 3 sequential merges
    f32x4* mrg = (f32x4*)smem;
#define MRG_IDX(si, sj) ((((wy * 2 + wx) * 4 + (si) * 2 + (sj)) * 4 + qy) * 16 + tx)
    __syncthreads();
    if (kh == 1) {
#pragma unroll
        for (int si = 0; si < 2; ++si)
#pragma unroll
            for (int sj = 0; sj < 2; ++sj) mrg[MRG_IDX(si, sj)] = accX[si][sj];
    }
    __syncthreads();
    if (kh == 0) {
#pragma unroll
        for (int si = 0; si < 2; ++si)
#pragma unroll
            for (int sj = 0; sj < 2; ++sj) {
                f32x4 o = mrg[MRG_IDX(si, sj)];
                accX[si][sj][0] += o[0]; accX[si][sj][1] += o[1];
                accX[si][sj][2] += o[2]; accX[si][sj][3] += o[3];
            }
    }
    __syncthreads();
    if (kh == 1) {
#pragma unroll
        for (int si = 0; si < 2; ++si)
#pragma unroll
            for (int sj = 0; sj < 2; ++sj) mrg[MRG_IDX(si, sj)] = accQ[si][sj];
    }
    __syncthreads();
    if (kh == 0) {
#pragma unroll
        for (int si = 0; si < 2; ++si)
#pragma unroll
            for (int sj = 0; sj < 2; ++sj) {
                f32x4 o = mrg[MRG_IDX(si, sj)];
                accQ[si][sj][0] += o[0]; accQ[si][sj][1] += o[1];
                accQ[si][sj][2] += o[2]; accQ[si][sj][3] += o[3];
            }
    }
    __syncthreads();
    if (kh == 1) {
#pragma unroll
        for (int si = 0; si < 2; ++si)
#pragma unroll
            for (int sj = 0; sj < 2; ++sj) mrg[MRG_IDX(si, sj)] = accP[si][sj];
    }
    __syncthreads();
    if (kh == 0) {
#pragma unroll
        for (int si = 0; si < 2; ++si)
#pragma unroll
            for (int sj = 0; sj < 2; ++sj) {
                f32x4 o = mrg[MRG_IDX(si, sj)];
                accP[si][sj][0] += o[0]; accP[si][sj][1] += o[1];
                accP[si][sj][2] += o[2]; accP[si][sj][3] += o[3];
            }
        // epilogue: out_q[i] += sum_m C_m*Mx*Mq ; out_p[i] += sum_m C_m*Mx*Mp
        float cm[2];
#pragma unroll
        for (int sj = 0; sj < 2; ++sj) {
            int m = m0 + wx * 32 + sj * 16 + tx;
            float hv = tanhf(Vacc[m] + b2[m]);
            float d2 = 1.f - hv * hv;
            cm[sj] = -2.f * hv * d2 * W3[m];
        }
#pragma unroll
        for (int si = 0; si < 2; ++si) {
            int ib = i0 + wy * 32 + si * 16 + qy * 4;
#pragma unroll
            for (int r = 0; r < 4; ++r) {
                int i = ib + r;
                float pq = 0.f, pp = 0.f;
#pragma unroll
                for (int sj = 0; sj < 2; ++sj) {
                    float mx = accX[si][sj][r];
                    pq += cm[sj] * mx * accQ[si][sj][r];
                    pp += cm[sj] * mx * accP[si][sj][r];
                }
                for (int o = 1; o < 16; o <<= 1) {
                    pq += __shfl_xor(pq, o);
                    pp += __shfl_xor(pp, o);
                }
                if (tx == 0) {
                    atomicAdd(&out[i], pp);
                    atomicAdd(&out[1024 + i], -pq);
                }
            }
        }
    }
}

extern "C" void kernel_launch(void* const* d_in, const int* in_sizes, int n_in,
                              void* d_out, int out_size, void* d_ws, size_t ws_size,
                              hipStream_t stream) {
    const float* x = (const float*)d_in[0];
    const float* q = (const float*)d_in[1];
    const float* p = (const float*)d_in[2];
    const float* W1 = (const float*)d_in[3];
    const float* b1 = (const float*)d_in[4];
    const float* W2 = (const float*)d_in[5];
    const float* b2 = (const float*)d_in[6];
    const float* W3 = (const float*)d_in[7];
    float* out = (float*)d_out;
    float* ws = (float*)d_ws;
    float* H1 = ws, *D1 = ws + 1024, *Vacc = ws + 3072;
    float* Upart = ws + 4096;  // 48*1024 floats
    u16* u0 = (u16*)(ws + 65536);
    u16* Ah = u0;              // 3072x1024 bf16 (all of W1)
    u16* WTh = u0 + 3145728;   // 1024x1024 bf16

    k_pre<<<195, 256, 0, stream>>>(x, q, p, W1, Ah, Upart, out, Vacc);
    k_w2v<<<dim3(16, 16), 256, 0, stream>>>(W2, b1, Upart, H1, D1, WTh, Vacc);
    k_big<<<320, 512, 0, stream>>>(Ah, WTh, W1, W2, b2, W3, Vacc, H1, D1, out);
}

// Round 5
// 123.103 us; speedup vs baseline: 1.9091x; 1.3389x over previous
//
#include <hip/hip_runtime.h>
#include <math.h>

typedef unsigned short u16;
typedef __bf16 bf16x8 __attribute__((ext_vector_type(8)));
typedef float f32x4 __attribute__((ext_vector_type(4)));

// ---------- helpers ----------
__device__ inline u16 bf16_rn(float x) {
    unsigned u = __float_as_uint(x);
    return (u16)((u + 0x7FFFu + ((u >> 16) & 1u)) >> 16);
}
__device__ inline uint2 pack4(u16 a, u16 b, u16 c, u16 d) {
    uint2 r;
    r.x = (unsigned)a | ((unsigned)b << 16);
    r.y = (unsigned)c | ((unsigned)d << 16);
    return r;
}
__device__ inline uint2 pack4f(float a, float b, float c, float d) {
    return pack4(bf16_rn(a), bf16_rn(b), bf16_rn(c), bf16_rn(d));
}
__device__ inline f32x4 mfma16(bf16x8 a, bf16x8 b, f32x4 c) {
    return __builtin_amdgcn_mfma_f32_16x16x32_bf16(a, b, c, 0, 0, 0);
}

// ---------- Node A: u-partials (0..191, A-block rows also emit bf16 cast) + zero (192..194) ----------
__global__ __launch_bounds__(256) void k_pre(const float* __restrict__ x,
                                             const float* __restrict__ q,
                                             const float* __restrict__ p,
                                             const float* __restrict__ W1,
                                             u16* __restrict__ Ah,
                                             float* __restrict__ Upart,
                                             float* __restrict__ out,
                                             float* __restrict__ Vacc) {
    int b = blockIdx.x, t = threadIdx.x;
    if (b < 192) {
        int jc = b;                    // 0..191
        int k = (jc & 3) * 256 + t;    // 4 k-groups
        int j0 = (jc >> 2) * 64;       // 48 j-chunks (64-aligned, never straddles x/q/p)
        __shared__ float zs[64];
        if (t < 64) {
            int j = j0 + t;
            zs[t] = (j < 1024) ? x[j] : (j < 2048 ? q[j - 1024] : p[j - 2048]);
        }
        __syncthreads();
        float acc = 0.f;
        if (j0 < 1024) {
            // A-block rows: fuse bf16 cast with the GEMV read (W1 A-block read once)
#pragma unroll 8
            for (int j = 0; j < 64; ++j) {
                float v = W1[(j0 + j) * 1024 + k];
                Ah[(j0 + j) * 1024 + k] = bf16_rn(v);
                acc += zs[j] * v;
            }
        } else {
#pragma unroll 8
            for (int j = 0; j < 64; ++j) acc += zs[j] * W1[(j0 + j) * 1024 + k];
        }
        Upart[(jc >> 2) * 1024 + k] = acc;  // plain store, no atomics
    } else {
        int idx = ((b - 192) * 256 + t) * 4;  // 3072 floats: out[2048] + Vacc[1024]
        if (idx < 2048) *(float4*)(out + idx) = make_float4(0.f, 0.f, 0.f, 0.f);
        else *(float4*)(Vacc + idx - 2048) = make_float4(0.f, 0.f, 0.f, 0.f);
    }
}

// ---------- Node C: reduce U -> h1/d1 (local), split W2 -> W2h, transpose+d1-scale
// -> WTh, Vacc partials; m0==0 blocks publish H1/D1 ----------
__global__ __launch_bounds__(256) void k_w2v(const float* __restrict__ W2,
                                             const float* __restrict__ b1,
                                             const float* __restrict__ Upart,
                                             float* __restrict__ H1g, float* __restrict__ D1g,
                                             u16* __restrict__ W2h,
                                             u16* __restrict__ WTh,
                                             float* __restrict__ Vacc) {
    __shared__ float T[64][65];
    __shared__ float hs[64], ds[64];
    __shared__ float red[4][64];
    int k0 = blockIdx.y * 64, m0 = blockIdx.x * 64;
    int t = threadIdx.x;
    {
        int lk = t & 63, g = t >> 6;  // 4 groups x 12 chunks
        float u = 0.f;
#pragma unroll
        for (int c = 0; c < 12; ++c) u += Upart[(g * 12 + c) * 1024 + k0 + lk];
        red[g][lk] = u;
    }
    __syncthreads();
    if (t < 64) {
        float u = red[0][t] + red[1][t] + red[2][t] + red[3][t];
        float h = tanhf(u + b1[k0 + t]);
        hs[t] = h;
        ds[t] = 1.f - h * h;
        if (m0 == 0) { H1g[k0 + t] = h; D1g[k0 + t] = 1.f - h * h; }
    }
    __syncthreads();
    int rr = t >> 4, cc = (t & 15) * 4;
    float4 vp = make_float4(0.f, 0.f, 0.f, 0.f);
#pragma unroll
    for (int j = 0; j < 4; ++j) {
        int r = rr + j * 16;
        float4 v = *(const float4*)(W2 + (k0 + r) * 1024 + m0 + cc);
        T[r][cc + 0] = v.x; T[r][cc + 1] = v.y; T[r][cc + 2] = v.z; T[r][cc + 3] = v.w;
        *(uint2*)&W2h[(k0 + r) * 1024 + m0 + cc] = pack4f(v.x, v.y, v.z, v.w);
        float hk = hs[r];
        vp.x += hk * v.x; vp.y += hk * v.y; vp.z += hk * v.z; vp.w += hk * v.w;
    }
    vp.x += __shfl_xor(vp.x, 16); vp.y += __shfl_xor(vp.y, 16);
    vp.z += __shfl_xor(vp.z, 16); vp.w += __shfl_xor(vp.w, 16);
    vp.x += __shfl_xor(vp.x, 32); vp.y += __shfl_xor(vp.y, 32);
    vp.z += __shfl_xor(vp.z, 32); vp.w += __shfl_xor(vp.w, 32);
    if (((t & 63) >> 4) == 0) {
        atomicAdd(&Vacc[m0 + cc + 0], vp.x);
        atomicAdd(&Vacc[m0 + cc + 1], vp.y);
        atomicAdd(&Vacc[m0 + cc + 2], vp.z);
        atomicAdd(&Vacc[m0 + cc + 3], vp.w);
    }
    __syncthreads();
#pragma unroll
    for (int j = 0; j < 4; ++j) {
        int mrow = rr + j * 16;
        float f0 = T[cc + 0][mrow] * ds[cc + 0];
        float f1 = T[cc + 1][mrow] * ds[cc + 1];
        float f2 = T[cc + 2][mrow] * ds[cc + 2];
        float f3 = T[cc + 3][mrow] * ds[cc + 3];
        *(uint2*)&WTh[(m0 + mrow) * 1024 + k0 + cc] = pack4f(f0, f1, f2, f3);
    }
}

// ---------- 64x32-tile dbuf BK=64 bf16 MFMA GEMMs, 512 threads, split-K waves ----------
// Tile narrowed 64x64 -> 64x32: grid doubles (512+ blocks) -> 2 blocks/CU co-resident
// -> 16 waves/CU (50% occupancy) for latency hiding. Per wave: 2 output frags (si),
// 1 col frag; 3 ds_read + 2 MFMA per K-step. B staged by waves 0-3 only (32 rows).
#define LDK 68
__global__ __launch_bounds__(512) void k_gemm1(const u16* __restrict__ Ah,
                                               const u16* __restrict__ Bh,
                                               const float* __restrict__ Vacc,
                                               const float* __restrict__ b2,
                                               const float* __restrict__ W3,
                                               const float* __restrict__ W2,
                                               const float* __restrict__ H1,
                                               const float* __restrict__ D1,
                                               float* __restrict__ Avec,
                                               u16* __restrict__ Sh) {
    __shared__ u16 As[2][64 * LDK];
    __shared__ u16 Bs[2][32 * LDK];
    __shared__ float sv[1024];
    int tid = threadIdx.x;
    if (blockIdx.x == 32) {
        // ---- Avec GEMV tail (R2-proven), 16 blocks x 64 k ----
        int kbase = blockIdx.y * 64;
#pragma unroll
        for (int j = 0; j < 2; ++j) {
            int m = tid + j * 512;
            float h = tanhf(Vacc[m] + b2[m]);
            sv[m] = (1.f - h * h) * W3[m];
        }
        __syncthreads();
        int g = tid >> 3, sub = tid & 7;
        int k = kbase + g;
        const float* wrow = W2 + k * 1024 + sub * 128;
        const float* svp = sv + sub * 128;
        float acc = 0.f;
#pragma unroll 8
        for (int j = 0; j < 128; ++j) acc += wrow[j] * svp[j];
        acc += __shfl_xor(acc, 1);
        acc += __shfl_xor(acc, 2);
        acc += __shfl_xor(acc, 4);
        if (sub == 0) Avec[k] = -2.f * H1[k] * D1[k] * acc;
        return;
    }
    int lane = tid & 63, wv = tid >> 6;  // wv 0..7
    int kh = wv >> 2, wy = (wv >> 1) & 1, wx = wv & 1;
    int i0 = blockIdx.y * 64, m0 = blockIdx.x * 32;
    int srow = tid >> 3, sseg = (tid & 7) * 8;
    int ldso = srow * LDK + sseg;
    const u16* ap = Ah + (i0 + srow) * 1024 + sseg;
    const u16* bp = Bh + (m0 + srow) * 1024 + sseg;  // valid rows only for srow<32
    bool stB = (tid < 256);                          // wave-uniform: waves 0-3 stage B
    int tx = lane & 15, qy = lane >> 4;
    int koff = kh * 32 + qy * 8;
    int raA0 = (wy * 32 + tx) * LDK + koff, raA1 = raA0 + 16 * LDK;
    int rbB0 = (wx * 16 + tx) * LDK + koff;
    f32x4 acc[2];
    acc[0] = (f32x4){0.f, 0.f, 0.f, 0.f};
    acc[1] = (f32x4){0.f, 0.f, 0.f, 0.f};

    uint4 pa1 = *(const uint4*)(ap + 64);  // depth-2 register prefetch
    uint4 pb1;
    if (stB) pb1 = *(const uint4*)(bp + 64);
    *(uint4*)&As[0][ldso] = *(const uint4*)(ap);
    if (stB) *(uint4*)&Bs[0][ldso] = *(const uint4*)(bp);

    for (int k0 = 0; k0 < 1024; k0 += 64) {
        int buf = (k0 >> 6) & 1;
        int kn2 = (k0 + 128) & 1023;  // wraps at tail; staged but never read
        uint4 pa2 = *(const uint4*)(ap + kn2);
        uint4 pb2;
        if (stB) pb2 = *(const uint4*)(bp + kn2);
        __syncthreads();
        bf16x8 aH0 = *(const bf16x8*)&As[buf][raA0];
        bf16x8 aH1 = *(const bf16x8*)&As[buf][raA1];
        bf16x8 bH0 = *(const bf16x8*)&Bs[buf][rbB0];
        acc[0] = mfma16(aH0, bH0, acc[0]);
        acc[1] = mfma16(aH1, bH0, acc[1]);
        int nb = buf ^ 1;
        *(uint4*)&As[nb][ldso] = pa1;
        if (stB) *(uint4*)&Bs[nb][ldso] = pb1;
        pa1 = pa2;
        if (stB) pb1 = pb2;
    }
    // merge K-halves through LDS (reuse As as scratch; 8 slots x 4 qy x 16 tx x f32x4 = 8 KB)
    __syncthreads();
    f32x4* mrg = (f32x4*)&As[0][0];
    if (kh == 1) {
#pragma unroll
        for (int si = 0; si < 2; ++si)
            mrg[((((wy * 2 + wx) * 2 + si) * 4 + qy) * 16 + tx)] = acc[si];
    }
    __syncthreads();
    if (kh == 0) {
#pragma unroll
        for (int si = 0; si < 2; ++si) {
            f32x4 o = mrg[((((wy * 2 + wx) * 2 + si) * 4 + qy) * 16 + tx)];
            acc[si][0] += o[0]; acc[si][1] += o[1];
            acc[si][2] += o[2]; acc[si][3] += o[3];
        }
        int m = m0 + wx * 16 + tx;
        float hv = tanhf(Vacc[m] + b2[m]);
        float d2 = 1.f - hv * hv;
        float cm = -2.f * hv * d2 * W3[m];  // Cvec inline
#pragma unroll
        for (int si = 0; si < 2; ++si) {
            int ib = i0 + wy * 32 + si * 16 + qy * 4;
#pragma unroll
            for (int r = 0; r < 4; ++r)
                Sh[(ib + r) * 1024 + m] = bf16_rn(acc[si][r] * cm);
        }
    }
}

__global__ __launch_bounds__(512) void k_gemm2(const u16* __restrict__ Sh,
                                               const u16* __restrict__ W2h,
                                               const float* __restrict__ W1,
                                               const float* __restrict__ D1,
                                               const float* __restrict__ Avec,
                                               float* __restrict__ out) {
    __shared__ u16 As[2][64 * LDK];
    __shared__ u16 Bs[2][32 * LDK];
    int tid = threadIdx.x, lane = tid & 63, wv = tid >> 6;
    int kh = wv >> 2, wy = (wv >> 1) & 1, wx = wv & 1;
    int i0 = blockIdx.y * 64, k0g = blockIdx.x * 32;
    int srow = tid >> 3, sseg = (tid & 7) * 8;
    int ldso = srow * LDK + sseg;
    const u16* ap = Sh + (i0 + srow) * 1024 + sseg;
    const u16* bp = W2h + (k0g + srow) * 1024 + sseg;  // valid rows only for srow<32
    bool stB = (tid < 256);
    int tx = lane & 15, qy = lane >> 4;
    int koff = kh * 32 + qy * 8;
    int raA0 = (wy * 32 + tx) * LDK + koff, raA1 = raA0 + 16 * LDK;
    int rbB0 = (wx * 16 + tx) * LDK + koff;
    f32x4 acc[2];
    acc[0] = (f32x4){0.f, 0.f, 0.f, 0.f};
    acc[1] = (f32x4){0.f, 0.f, 0.f, 0.f};

    uint4 pa1 = *(const uint4*)(ap + 64);
    uint4 pb1;
    if (stB) pb1 = *(const uint4*)(bp + 64);
    *(uint4*)&As[0][ldso] = *(const uint4*)(ap);
    if (stB) *(uint4*)&Bs[0][ldso] = *(const uint4*)(bp);

    for (int m0 = 0; m0 < 1024; m0 += 64) {
        int buf = (m0 >> 6) & 1;
        int mn2 = (m0 + 128) & 1023;
        uint4 pa2 = *(const uint4*)(ap + mn2);
        uint4 pb2;
        if (stB) pb2 = *(const uint4*)(bp + mn2);
        __syncthreads();
        bf16x8 aH0 = *(const bf16x8*)&As[buf][raA0];
        bf16x8 aH1 = *(const bf16x8*)&As[buf][raA1];
        bf16x8 bH0 = *(const bf16x8*)&Bs[buf][rbB0];
        acc[0] = mfma16(aH0, bH0, acc[0]);
        acc[1] = mfma16(aH1, bH0, acc[1]);
        int nb = buf ^ 1;
        *(uint4*)&As[nb][ldso] = pa1;
        if (stB) *(uint4*)&Bs[nb][ldso] = pb1;
        pa1 = pa2;
        if (stB) pb1 = pb2;
    }
    // merge K-halves through LDS
    __syncthreads();
    f32x4* mrg = (f32x4*)&As[0][0];
    if (kh == 1) {
#pragma unroll
        for (int si = 0; si < 2; ++si)
            mrg[((((wy * 2 + wx) * 2 + si) * 4 + qy) * 16 + tx)] = acc[si];
    }
    __syncthreads();
    if (kh == 0) {
#pragma unroll
        for (int si = 0; si < 2; ++si) {
            f32x4 o = mrg[((((wy * 2 + wx) * 2 + si) * 4 + qy) * 16 + tx)];
            acc[si][0] += o[0]; acc[si][1] += o[1];
            acc[si][2] += o[2]; acc[si][3] += o[3];
        }
        // fused epilogue: DR = Avec[k]*W1[i,k] + D1[k]*Wm[i,k]; dot with q/p rows of W1
        int kk = k0g + wx * 16 + tx;
        float d1v = D1[kk], avv = Avec[kk];
#pragma unroll
        for (int si = 0; si < 2; ++si) {
            int ib = i0 + wy * 32 + si * 16 + qy * 4;
#pragma unroll
            for (int r = 0; r < 4; ++r) {
                int i = ib + r;
                float dr = avv * W1[i * 1024 + kk] + d1v * acc[si][r];
                float pq = W1[(1024 + i) * 1024 + kk] * dr;
                float pp = W1[(2048 + i) * 1024 + kk] * dr;
                for (int o = 1; o < 16; o <<= 1) {
                    pq += __shfl_xor(pq, o);
                    pp += __shfl_xor(pp, o);
                }
                if (tx == 0) {
                    atomicAdd(&out[i], pp);
                    atomicAdd(&out[1024 + i], -pq);
                }
            }
        }
    }
}

extern "C" void kernel_launch(void* const* d_in, const int* in_sizes, int n_in,
                              void* d_out, int out_size, void* d_ws, size_t ws_size,
                              hipStream_t stream) {
    const float* x = (const float*)d_in[0];
    const float* q = (const float*)d_in[1];
    const float* p = (const float*)d_in[2];
    const float* W1 = (const float*)d_in[3];
    const float* b1 = (const float*)d_in[4];
    const float* W2 = (const float*)d_in[5];
    const float* b2 = (const float*)d_in[6];
    const float* W3 = (const float*)d_in[7];
    float* out = (float*)d_out;
    float* ws = (float*)d_ws;
    float* H1 = ws, *D1 = ws + 1024, *Avec = ws + 2048, *Vacc = ws + 3072;
    float* Upart = ws + 4096;  // 48*1024 floats
    u16* u0 = (u16*)(ws + 65536);
    u16* Ah = u0;
    u16* WTh = u0 + 1048576;
    u16* W2h = u0 + 2097152;
    u16* Sh = u0 + 3145728;

    k_pre<<<195, 256, 0, stream>>>(x, q, p, W1, Ah, Upart, out, Vacc);
    k_w2v<<<dim3(16, 16), 256, 0, stream>>>(W2, b1, Upart, H1, D1, W2h, WTh, Vacc);
    k_gemm1<<<dim3(33, 16), 512, 0, stream>>>(Ah, WTh, Vacc, b2, W3, W2, H1, D1, Avec, Sh);
    k_gemm2<<<dim3(32, 16), 512, 0, stream>>>(Sh, W2h, W1, D1, Avec, out);
}

// Round 6
// 114.814 us; speedup vs baseline: 2.0469x; 1.0722x over previous
//
#include <hip/hip_runtime.h>
#include <math.h>

typedef unsigned short u16;
typedef __bf16 bf16x8 __attribute__((ext_vector_type(8)));
typedef float f32x4 __attribute__((ext_vector_type(4)));

// ---------- helpers ----------
__device__ inline u16 bf16_rn(float x) {
    unsigned u = __float_as_uint(x);
    return (u16)((u + 0x7FFFu + ((u >> 16) & 1u)) >> 16);
}
__device__ inline uint2 pack4(u16 a, u16 b, u16 c, u16 d) {
    uint2 r;
    r.x = (unsigned)a | ((unsigned)b << 16);
    r.y = (unsigned)c | ((unsigned)d << 16);
    return r;
}
__device__ inline uint2 pack4f(float a, float b, float c, float d) {
    return pack4(bf16_rn(a), bf16_rn(b), bf16_rn(c), bf16_rn(d));
}
__device__ inline f32x4 mfma16(bf16x8 a, bf16x8 b, f32x4 c) {
    return __builtin_amdgcn_mfma_f32_16x16x32_bf16(a, b, c, 0, 0, 0);
}

// ---------- Node A: u-partials, 32-j chunks (384 blocks -> 1.5 waves/SIMD; was 192/0.75)
//            A-block rows also emit bf16 cast; blocks 384..386 zero out/Vacc ----------
__global__ __launch_bounds__(256) void k_pre(const float* __restrict__ x,
                                             const float* __restrict__ q,
                                             const float* __restrict__ p,
                                             const float* __restrict__ W1,
                                             u16* __restrict__ Ah,
                                             float* __restrict__ Upart,
                                             float* __restrict__ out,
                                             float* __restrict__ Vacc) {
    int b = blockIdx.x, t = threadIdx.x;
    if (b < 384) {
        int jc = b;                    // 0..383
        int k = (jc & 3) * 256 + t;    // 4 k-groups
        int j0 = (jc >> 2) * 32;       // 96 j-chunks (32-aligned; x/q/p boundaries at 1024/2048 respected)
        __shared__ float zs[32];
        if (t < 32) {
            int j = j0 + t;
            zs[t] = (j < 1024) ? x[j] : (j < 2048 ? q[j - 1024] : p[j - 2048]);
        }
        __syncthreads();
        float acc = 0.f;
        if (j0 < 1024) {
            // A-block rows: fuse bf16 cast with the GEMV read (W1 A-block read once)
#pragma unroll 8
            for (int j = 0; j < 32; ++j) {
                float v = W1[(j0 + j) * 1024 + k];
                Ah[(j0 + j) * 1024 + k] = bf16_rn(v);
                acc += zs[j] * v;
            }
        } else {
#pragma unroll 8
            for (int j = 0; j < 32; ++j) acc += zs[j] * W1[(j0 + j) * 1024 + k];
        }
        Upart[(jc >> 2) * 1024 + k] = acc;  // plain store, no atomics (96 partials/k)
    } else {
        int idx = ((b - 384) * 256 + t) * 4;  // 3072 floats: out[2048] + Vacc[1024]
        if (idx < 2048) *(float4*)(out + idx) = make_float4(0.f, 0.f, 0.f, 0.f);
        else *(float4*)(Vacc + idx - 2048) = make_float4(0.f, 0.f, 0.f, 0.f);
    }
}

// ---------- Node C: reduce U (96 partials) -> h1/d1, split W2 -> W2h, transpose+d1-scale
// -> WTh, Vacc partials; m0==0 blocks publish H1/D1 ----------
__global__ __launch_bounds__(256) void k_w2v(const float* __restrict__ W2,
                                             const float* __restrict__ b1,
                                             const float* __restrict__ Upart,
                                             float* __restrict__ H1g, float* __restrict__ D1g,
                                             u16* __restrict__ W2h,
                                             u16* __restrict__ WTh,
                                             float* __restrict__ Vacc) {
    __shared__ float T[64][65];
    __shared__ float hs[64], ds[64];
    __shared__ float red[4][64];
    int k0 = blockIdx.y * 64, m0 = blockIdx.x * 64;
    int t = threadIdx.x;
    {
        int lk = t & 63, g = t >> 6;  // 4 groups x 24 chunks
        float u = 0.f;
#pragma unroll
        for (int c = 0; c < 24; ++c) u += Upart[(g * 24 + c) * 1024 + k0 + lk];
        red[g][lk] = u;
    }
    __syncthreads();
    if (t < 64) {
        float u = red[0][t] + red[1][t] + red[2][t] + red[3][t];
        float h = tanhf(u + b1[k0 + t]);
        hs[t] = h;
        ds[t] = 1.f - h * h;
        if (m0 == 0) { H1g[k0 + t] = h; D1g[k0 + t] = 1.f - h * h; }
    }
    __syncthreads();
    int rr = t >> 4, cc = (t & 15) * 4;
    float4 vp = make_float4(0.f, 0.f, 0.f, 0.f);
#pragma unroll
    for (int j = 0; j < 4; ++j) {
        int r = rr + j * 16;
        float4 v = *(const float4*)(W2 + (k0 + r) * 1024 + m0 + cc);
        T[r][cc + 0] = v.x; T[r][cc + 1] = v.y; T[r][cc + 2] = v.z; T[r][cc + 3] = v.w;
        *(uint2*)&W2h[(k0 + r) * 1024 + m0 + cc] = pack4f(v.x, v.y, v.z, v.w);
        float hk = hs[r];
        vp.x += hk * v.x; vp.y += hk * v.y; vp.z += hk * v.z; vp.w += hk * v.w;
    }
    vp.x += __shfl_xor(vp.x, 16); vp.y += __shfl_xor(vp.y, 16);
    vp.z += __shfl_xor(vp.z, 16); vp.w += __shfl_xor(vp.w, 16);
    vp.x += __shfl_xor(vp.x, 32); vp.y += __shfl_xor(vp.y, 32);
    vp.z += __shfl_xor(vp.z, 32); vp.w += __shfl_xor(vp.w, 32);
    if (((t & 63) >> 4) == 0) {
        atomicAdd(&Vacc[m0 + cc + 0], vp.x);
        atomicAdd(&Vacc[m0 + cc + 1], vp.y);
        atomicAdd(&Vacc[m0 + cc + 2], vp.z);
        atomicAdd(&Vacc[m0 + cc + 3], vp.w);
    }
    __syncthreads();
#pragma unroll
    for (int j = 0; j < 4; ++j) {
        int mrow = rr + j * 16;
        float f0 = T[cc + 0][mrow] * ds[cc + 0];
        float f1 = T[cc + 1][mrow] * ds[cc + 1];
        float f2 = T[cc + 2][mrow] * ds[cc + 2];
        float f3 = T[cc + 3][mrow] * ds[cc + 3];
        *(uint2*)&WTh[(m0 + mrow) * 1024 + k0 + cc] = pack4f(f0, f1, f2, f3);
    }
}

// ---------- dbuf BK=64 pure-bf16 MFMA GEMMs, 512 threads, split-K waves (R2-proven) ----------
#define LDK 68
__global__ __launch_bounds__(512) void k_gemm1(const u16* __restrict__ Ah,
                                               const u16* __restrict__ Bh,
                                               const float* __restrict__ Vacc,
                                               const float* __restrict__ b2,
                                               const float* __restrict__ W3,
                                               const float* __restrict__ W2,
                                               const float* __restrict__ H1,
                                               const float* __restrict__ D1,
                                               float* __restrict__ Avec,
                                               u16* __restrict__ Sh) {
    __shared__ u16 As[2][64 * LDK];
    __shared__ u16 Bs[2][64 * LDK];
    __shared__ float sv[1024];
    int tid = threadIdx.x;
    if (blockIdx.x == 16) {
        // ---- Avec GEMV tail, 16 blocks x 64 k ----
        int kbase = blockIdx.y * 64;
#pragma unroll
        for (int j = 0; j < 2; ++j) {
            int m = tid + j * 512;
            float h = tanhf(Vacc[m] + b2[m]);
            sv[m] = (1.f - h * h) * W3[m];
        }
        __syncthreads();
        int g = tid >> 3, sub = tid & 7;
        int k = kbase + g;
        const float* wrow = W2 + k * 1024 + sub * 128;
        const float* svp = sv + sub * 128;
        float acc = 0.f;
#pragma unroll 8
        for (int j = 0; j < 128; ++j) acc += wrow[j] * svp[j];
        acc += __shfl_xor(acc, 1);
        acc += __shfl_xor(acc, 2);
        acc += __shfl_xor(acc, 4);
        if (sub == 0) Avec[k] = -2.f * H1[k] * D1[k] * acc;
        return;
    }
    int lane = tid & 63, wv = tid >> 6;  // wv 0..7
    int kh = wv >> 2, wy = (wv >> 1) & 1, wx = wv & 1;
    int i0 = blockIdx.y * 64, m0 = blockIdx.x * 64;
    int srow = tid >> 3, sseg = (tid & 7) * 8;
    int ldso = srow * LDK + sseg;
    const u16* ap = Ah + (i0 + srow) * 1024 + sseg;
    const u16* bp = Bh + (m0 + srow) * 1024 + sseg;
    int tx = lane & 15, qy = lane >> 4;
    int koff = kh * 32 + qy * 8;
    int raA[2], rbB[2];
    raA[0] = (wy * 32 + tx) * LDK + koff;
    raA[1] = raA[0] + 16 * LDK;
    rbB[0] = (wx * 32 + tx) * LDK + koff;
    rbB[1] = rbB[0] + 16 * LDK;
    f32x4 acc[2][2];
#pragma unroll
    for (int a = 0; a < 2; ++a)
#pragma unroll
        for (int b = 0; b < 2; ++b) acc[a][b] = (f32x4){0.f, 0.f, 0.f, 0.f};

    uint4 pa1 = *(const uint4*)(ap + 64);   // depth-2 register prefetch
    uint4 pc1 = *(const uint4*)(bp + 64);
    *(uint4*)&As[0][ldso] = *(const uint4*)(ap);
    *(uint4*)&Bs[0][ldso] = *(const uint4*)(bp);

    for (int k0 = 0; k0 < 1024; k0 += 64) {
        int buf = (k0 >> 6) & 1;
        int kn2 = (k0 + 128) & 1023;  // wraps at tail; staged but never read
        uint4 pa2 = *(const uint4*)(ap + kn2);
        uint4 pc2 = *(const uint4*)(bp + kn2);
        __syncthreads();
        bf16x8 aH0 = *(const bf16x8*)&As[buf][raA[0]];
        bf16x8 aH1 = *(const bf16x8*)&As[buf][raA[1]];
        bf16x8 bH0 = *(const bf16x8*)&Bs[buf][rbB[0]];
        bf16x8 bH1 = *(const bf16x8*)&Bs[buf][rbB[1]];
        acc[0][0] = mfma16(aH0, bH0, acc[0][0]);
        acc[0][1] = mfma16(aH0, bH1, acc[0][1]);
        acc[1][0] = mfma16(aH1, bH0, acc[1][0]);
        acc[1][1] = mfma16(aH1, bH1, acc[1][1]);
        int nb = buf ^ 1;
        *(uint4*)&As[nb][ldso] = pa1;
        *(uint4*)&Bs[nb][ldso] = pc1;
        pa1 = pa2; pc1 = pc2;
    }
    // merge K-halves through LDS (reuse As as scratch)
    __syncthreads();
    f32x4* mrg = (f32x4*)&As[0][0];
    if (kh == 1) {
#pragma unroll
        for (int si = 0; si < 2; ++si)
#pragma unroll
            for (int sj = 0; sj < 2; ++sj)
                mrg[(((wy * 2 + wx) * 4 + si * 2 + sj) * 4 + qy) * 16 + tx] = acc[si][sj];
    }
    __syncthreads();
    if (kh == 0) {
#pragma unroll
        for (int si = 0; si < 2; ++si)
#pragma unroll
            for (int sj = 0; sj < 2; ++sj) {
                f32x4 o = mrg[(((wy * 2 + wx) * 4 + si * 2 + sj) * 4 + qy) * 16 + tx];
                acc[si][sj][0] += o[0]; acc[si][sj][1] += o[1];
                acc[si][sj][2] += o[2]; acc[si][sj][3] += o[3];
            }
#pragma unroll
        for (int sj = 0; sj < 2; ++sj) {
            int m = m0 + wx * 32 + sj * 16 + tx;
            float hv = tanhf(Vacc[m] + b2[m]);
            float d2 = 1.f - hv * hv;
            float cm = -2.f * hv * d2 * W3[m];  // Cvec inline
#pragma unroll
            for (int si = 0; si < 2; ++si) {
                int ib = i0 + wy * 32 + si * 16 + qy * 4;
#pragma unroll
                for (int r = 0; r < 4; ++r)
                    Sh[(ib + r) * 1024 + m] = bf16_rn(acc[si][sj][r] * cm);
            }
        }
    }
}

__global__ __launch_bounds__(512) void k_gemm2(const u16* __restrict__ Sh,
                                               const u16* __restrict__ W2h,
                                               const float* __restrict__ W1,
                                               const float* __restrict__ D1,
                                               const float* __restrict__ Avec,
                                               float* __restrict__ out) {
    __shared__ u16 As[2][64 * LDK];
    __shared__ u16 Bs[2][64 * LDK];
    int tid = threadIdx.x, lane = tid & 63, wv = tid >> 6;
    int kh = wv >> 2, wy = (wv >> 1) & 1, wx = wv & 1;
    int i0 = blockIdx.y * 64, k0g = blockIdx.x * 64;
    int srow = tid >> 3, sseg = (tid & 7) * 8;
    int ldso = srow * LDK + sseg;
    const u16* ap = Sh + (i0 + srow) * 1024 + sseg;
    const u16* bp = W2h + (k0g + srow) * 1024 + sseg;
    int tx = lane & 15, qy = lane >> 4;
    int koff = kh * 32 + qy * 8;
    int raA[2], rbB[2];
    raA[0] = (wy * 32 + tx) * LDK + koff;
    raA[1] = raA[0] + 16 * LDK;
    rbB[0] = (wx * 32 + tx) * LDK + koff;
    rbB[1] = rbB[0] + 16 * LDK;
    f32x4 acc[2][2];
#pragma unroll
    for (int a = 0; a < 2; ++a)
#pragma unroll
        for (int b = 0; b < 2; ++b) acc[a][b] = (f32x4){0.f, 0.f, 0.f, 0.f};

    uint4 pa1 = *(const uint4*)(ap + 64);
    uint4 pc1 = *(const uint4*)(bp + 64);
    *(uint4*)&As[0][ldso] = *(const uint4*)(ap);
    *(uint4*)&Bs[0][ldso] = *(const uint4*)(bp);

    for (int m0 = 0; m0 < 1024; m0 += 64) {
        int buf = (m0 >> 6) & 1;
        int mn2 = (m0 + 128) & 1023;
        uint4 pa2 = *(const uint4*)(ap + mn2);
        uint4 pc2 = *(const uint4*)(bp + mn2);
        __syncthreads();
        bf16x8 aH0 = *(const bf16x8*)&As[buf][raA[0]];
        bf16x8 aH1 = *(const bf16x8*)&As[buf][raA[1]];
        bf16x8 bH0 = *(const bf16x8*)&Bs[buf][rbB[0]];
        bf16x8 bH1 = *(const bf16x8*)&Bs[buf][rbB[1]];
        acc[0][0] = mfma16(aH0, bH0, acc[0][0]);
        acc[0][1] = mfma16(aH0, bH1, acc[0][1]);
        acc[1][0] = mfma16(aH1, bH0, acc[1][0]);
        acc[1][1] = mfma16(aH1, bH1, acc[1][1]);
        int nb = buf ^ 1;
        *(uint4*)&As[nb][ldso] = pa1;
        *(uint4*)&Bs[nb][ldso] = pc1;
        pa1 = pa2; pc1 = pc2;
    }
    // merge K-halves through LDS
    __syncthreads();
    f32x4* mrg = (f32x4*)&As[0][0];
    if (kh == 1) {
#pragma unroll
        for (int si = 0; si < 2; ++si)
#pragma unroll
            for (int sj = 0; sj < 2; ++sj)
                mrg[(((wy * 2 + wx) * 4 + si * 2 + sj) * 4 + qy) * 16 + tx] = acc[si][sj];
    }
    __syncthreads();
    if (kh == 0) {
#pragma unroll
        for (int si = 0; si < 2; ++si)
#pragma unroll
            for (int sj = 0; sj < 2; ++sj) {
                f32x4 o = mrg[(((wy * 2 + wx) * 4 + si * 2 + sj) * 4 + qy) * 16 + tx];
                acc[si][sj][0] += o[0]; acc[si][sj][1] += o[1];
                acc[si][sj][2] += o[2]; acc[si][sj][3] += o[3];
            }
        // fused epilogue: DR = Avec[k]*W1[i,k] + D1[k]*Wm[i,k]; dot with q/p rows of W1
        int kk[2];
        float d1v[2], avv[2];
#pragma unroll
        for (int sj = 0; sj < 2; ++sj) {
            kk[sj] = k0g + wx * 32 + sj * 16 + tx;
            d1v[sj] = D1[kk[sj]];
            avv[sj] = Avec[kk[sj]];
        }
#pragma unroll
        for (int si = 0; si < 2; ++si) {
            int ib = i0 + wy * 32 + si * 16 + qy * 4;
#pragma unroll
            for (int r = 0; r < 4; ++r) {
                int i = ib + r;
                float pq = 0.f, pp = 0.f;
#pragma unroll
                for (int sj = 0; sj < 2; ++sj) {
                    int k = kk[sj];
                    float dr = avv[sj] * W1[i * 1024 + k] + d1v[sj] * acc[si][sj][r];
                    pq += W1[(1024 + i) * 1024 + k] * dr;
                    pp += W1[(2048 + i) * 1024 + k] * dr;
                }
                for (int o = 1; o < 16; o <<= 1) {
                    pq += __shfl_xor(pq, o);
                    pp += __shfl_xor(pp, o);
                }
                if (tx == 0) {
                    atomicAdd(&out[i], pp);
                    atomicAdd(&out[1024 + i], -pq);
                }
            }
        }
    }
}

extern "C" void kernel_launch(void* const* d_in, const int* in_sizes, int n_in,
                              void* d_out, int out_size, void* d_ws, size_t ws_size,
                              hipStream_t stream) {
    const float* x = (const float*)d_in[0];
    const float* q = (const float*)d_in[1];
    const float* p = (const float*)d_in[2];
    const float* W1 = (const float*)d_in[3];
    const float* b1 = (const float*)d_in[4];
    const float* W2 = (const float*)d_in[5];
    const float* b2 = (const float*)d_in[6];
    const float* W3 = (const float*)d_in[7];
    float* out = (float*)d_out;
    float* ws = (float*)d_ws;
    float* H1 = ws, *D1 = ws + 1024, *Avec = ws + 2048, *Vacc = ws + 3072;
    float* Upart = ws + 4096;         // 96*1024 floats (384 KB)
    u16* u0 = (u16*)(ws + 131072);    // bf16 arena moved past enlarged Upart
    u16* Ah = u0;
    u16* WTh = u0 + 1048576;
    u16* W2h = u0 + 2097152;
    u16* Sh = u0 + 3145728;

    k_pre<<<387, 256, 0, stream>>>(x, q, p, W1, Ah, Upart, out, Vacc);
    k_w2v<<<dim3(16, 16), 256, 0, stream>>>(W2, b1, Upart, H1, D1, W2h, WTh, Vacc);
    k_gemm1<<<dim3(17, 16), 512, 0, stream>>>(Ah, WTh, Vacc, b2, W3, W2, H1, D1, Avec, Sh);
    k_gemm2<<<dim3(16, 16), 512, 0, stream>>>(Sh, W2h, W1, D1, Avec, out);
}